// Round 1
// baseline (49.799 us; speedup 1.0000x reference)
//
#include <hip/hip_runtime.h>
#include <stdint.h>

// HeteNet distribute_compute: T=64, N=64, D=512, H=512, A=32, E=15
#define NTOK 4096   // T*N tokens
#define DDIM 512    // obs dim
#define HDIM 512    // hidden
#define ADIM 32     // actions
#define NEXP 15     // experts
#define TILE_M 32   // tokens per compute tile
#define KBLK 64     // K chunk staged per barrier
#define NTILE (NTOK / TILE_M)  // 128 (worst case: all tokens on one expert)

typedef __attribute__((ext_vector_type(8))) short bf16x8;
typedef __attribute__((ext_vector_type(8))) unsigned short ushort8;
typedef __attribute__((ext_vector_type(4))) float f32x4;

__device__ __forceinline__ unsigned short f2bf(float f) {
  unsigned int u = __float_as_uint(f);
  u += 0x7fffu + ((u >> 16) & 1u);   // round-to-nearest-even
  return (unsigned short)(u >> 16);
}

// ---------------- prep: W transpose+bf16 convert, token bucketing ----------------
#define NB_W1 (NEXP * 16 * 16)   // 3840 blocks: W1 [E][D][H] -> W1T bf16 [E][H][D]
#define NB_W2 (NEXP * 16)        // 240  blocks: W2 [E][H][A] -> W2T bf16 [E][A][H]

__global__ __launch_bounds__(256) void prep_kernel(
    const float* __restrict__ W1, const float* __restrict__ W2,
    const int* __restrict__ pick, int* __restrict__ counts,
    int* __restrict__ lists, unsigned short* __restrict__ W1T,
    unsigned short* __restrict__ W2T)
{
  const int bid = blockIdx.x;
  const int tid = threadIdx.x;
  if (bid < NB_W1) {
    __shared__ float tile[32][33];
    const int e = bid >> 8, rem = bid & 255, ti = rem >> 4, tj = rem & 15;
    const float* src = W1 + (size_t)e * (DDIM * HDIM);
    unsigned short* dst = W1T + (size_t)e * (HDIM * DDIM);
    const int tx = tid & 31, ty = tid >> 5;
    const int r0 = ti * 32, c0 = tj * 32;  // r0: k, c0: n
    #pragma unroll
    for (int r = 0; r < 4; ++r)
      tile[ty + r * 8][tx] = src[(size_t)(r0 + ty + r * 8) * HDIM + (c0 + tx)];
    __syncthreads();
    #pragma unroll
    for (int r = 0; r < 4; ++r)
      dst[(size_t)(c0 + ty + r * 8) * DDIM + (r0 + tx)] = f2bf(tile[tx][ty + r * 8]);
  } else if (bid < NB_W1 + NB_W2) {
    __shared__ float tile2[32][33];
    const int b = bid - NB_W1, e = b >> 4, ti = b & 15;
    const float* src = W2 + (size_t)e * (HDIM * ADIM);
    unsigned short* dst = W2T + (size_t)e * (ADIM * HDIM);
    const int tx = tid & 31, ty = tid >> 5;
    const int r0 = ti * 32;   // k window; cols are the full A=32
    #pragma unroll
    for (int r = 0; r < 4; ++r)
      tile2[ty + r * 8][tx] = src[(size_t)(r0 + ty + r * 8) * ADIM + tx];
    __syncthreads();
    #pragma unroll
    for (int r = 0; r < 4; ++r)
      dst[(size_t)(ty + r * 8) * HDIM + (r0 + tx)] = f2bf(tile2[tx][ty + r * 8]);
  } else {
    // ordered (deterministic) per-expert compaction: 256 threads x 16 tokens each
    __shared__ int s_inc[NEXP][256];
    __shared__ int s_run[NEXP][256];
    int pk[16];
    #pragma unroll
    for (int i = 0; i < 16; ++i) pk[i] = pick[tid * 16 + i];
    #pragma unroll
    for (int e = 0; e < NEXP; ++e) {
      int c = 0;
      #pragma unroll
      for (int i = 0; i < 16; ++i) c += (pk[i] == e) ? 1 : 0;
      s_inc[e][tid] = c;
    }
    __syncthreads();
    for (int off = 1; off < 256; off <<= 1) {   // Hillis-Steele inclusive scan
      int v[NEXP];
      #pragma unroll
      for (int e = 0; e < NEXP; ++e) v[e] = (tid >= off) ? s_inc[e][tid - off] : 0;
      __syncthreads();
      #pragma unroll
      for (int e = 0; e < NEXP; ++e) s_inc[e][tid] += v[e];
      __syncthreads();
    }
    #pragma unroll
    for (int e = 0; e < NEXP; ++e) s_run[e][tid] = (tid > 0) ? s_inc[e][tid - 1] : 0;
    __syncthreads();
    #pragma unroll
    for (int i = 0; i < 16; ++i) {
      int p = pk[i];
      int pos = s_run[p][tid]++;
      lists[p * NTOK + pos] = tid * 16 + i;
    }
    if (tid < NEXP) counts[tid] = s_inc[tid][255];
  }
}

// ---------------- fused grouped 2-layer MLP, bf16 MFMA ----------------
// LDS: s_x = [32][512] bf16 (32KB, XOR-swizzled 16B slots; reused for h)
//      s_w = [512][64] bf16 W1T K-chunk (64KB; reused as [32][512] for W2T)
__global__ __launch_bounds__(256, 1) void moe_gemm(
    const float* __restrict__ obs, const float* __restrict__ b1,
    const float* __restrict__ b2, const int* __restrict__ counts,
    const int* __restrict__ lists, const unsigned short* __restrict__ W1T,
    const unsigned short* __restrict__ W2T, float* __restrict__ out)
{
  const int e = blockIdx.y;
  const int cnt = counts[e];
  const int tile_lo = blockIdx.x * TILE_M;
  if (tile_lo >= cnt) return;
  int mvalid = cnt - tile_lo; if (mvalid > TILE_M) mvalid = TILE_M;

  extern __shared__ char smem[];
  char* s_x = smem;            // 32KB
  char* s_w = smem + 32768;    // 64KB

  const int tid = threadIdx.x;
  const int lane = tid & 63;
  const int wave = tid >> 6;
  const int l15 = lane & 15, l4 = lane >> 4;
  const int* mylist = lists + e * NTOK;
  const unsigned short* w1t_e = W1T + (size_t)e * (HDIM * DDIM);
  const unsigned short* w2t_e = W2T + (size_t)e * (ADIM * HDIM);

  // ---- stage X: gather 32 obs rows, fp32->bf16, swizzled rows of 1KB
  {
    const int m = tid >> 3, s8 = tid & 7;
    int idx = tile_lo + m; if (idx >= cnt) idx = cnt - 1;   // pad with a valid token
    const float* grow = obs + (size_t)mylist[idx] * DDIM;
    #pragma unroll
    for (int si = 0; si < 8; ++si) {
      int s = s8 + si * 8;
      float4 f0 = *(const float4*)(grow + s * 8);
      float4 f1 = *(const float4*)(grow + s * 8 + 4);
      ushort8 v;
      v[0] = f2bf(f0.x); v[1] = f2bf(f0.y); v[2] = f2bf(f0.z); v[3] = f2bf(f0.w);
      v[4] = f2bf(f1.x); v[5] = f2bf(f1.y); v[6] = f2bf(f1.z); v[7] = f2bf(f1.w);
      *(ushort8*)(s_x + m * 1024 + ((s ^ (m & 7)) << 4)) = v;
    }
  }

  // ---- GEMM1: C1[32][512] = X @ W1[e], acc in f32
  f32x4 zero = {0.f, 0.f, 0.f, 0.f};
  f32x4 acc[2][8];
  #pragma unroll
  for (int mt = 0; mt < 2; ++mt)
    #pragma unroll
    for (int nt = 0; nt < 8; ++nt) acc[mt][nt] = zero;

  const int nbase = wave * 128;  // each wave owns 128 cols of H

  auto stage_w1 = [&](int kb) {
    #pragma unroll
    for (int i = 0; i < 16; ++i) {
      int n = i * 32 + (tid >> 3);
      int s = tid & 7;
      ushort8 v = *(const ushort8*)(w1t_e + (size_t)n * DDIM + kb * KBLK + s * 8);
      *(ushort8*)(s_w + n * 128 + ((s ^ (n & 7)) << 4)) = v;
    }
  };

  stage_w1(0);
  __syncthreads();

  for (int kb = 0; kb < 8; ++kb) {
    #pragma unroll
    for (int kk = 0; kk < 2; ++kk) {
      bf16x8 afr[2];
      #pragma unroll
      for (int mt = 0; mt < 2; ++mt) {
        int m = mt * 16 + l15;
        int sg = kb * 8 + kk * 4 + l4;
        afr[mt] = *(const bf16x8*)(s_x + m * 1024 + ((sg ^ (m & 7)) << 4));
      }
      #pragma unroll
      for (int nt = 0; nt < 8; ++nt) {
        int n = nbase + nt * 16 + l15;
        int sgw = kk * 4 + l4;
        bf16x8 bfr = *(const bf16x8*)(s_w + n * 128 + ((sgw ^ (n & 7)) << 4));
        acc[0][nt] = __builtin_amdgcn_mfma_f32_16x16x32_bf16(afr[0], bfr, acc[0][nt], 0, 0, 0);
        acc[1][nt] = __builtin_amdgcn_mfma_f32_16x16x32_bf16(afr[1], bfr, acc[1][nt], 0, 0, 0);
      }
    }
    __syncthreads();
    if (kb < 7) { stage_w1(kb + 1); __syncthreads(); }
  }

  // ---- h = relu(C1 + b1) -> bf16 into s_x (X fully consumed; barrier above)
  #pragma unroll
  for (int nt = 0; nt < 8; ++nt) {
    int n = nbase + nt * 16 + l15;
    float bias = b1[e * HDIM + n];
    #pragma unroll
    for (int mt = 0; mt < 2; ++mt) {
      #pragma unroll
      for (int r = 0; r < 4; ++r) {
        int m = mt * 16 + l4 * 4 + r;   // C/D: row=(lane>>4)*4+reg, col=lane&15
        float v = acc[mt][nt][r] + bias;
        v = v > 0.f ? v : 0.f;
        *(unsigned short*)(s_x + m * 1024 + (((n >> 3) ^ (m & 7)) << 4) + ((n & 7) << 1)) = f2bf(v);
      }
    }
  }
  // ---- stage W2T -> s_w as [32][512] bf16 (swizzled)
  #pragma unroll
  for (int i = 0; i < 8; ++i) {
    int a = tid >> 3;
    int s = (tid & 7) + i * 8;
    ushort8 v = *(const ushort8*)(w2t_e + (size_t)a * HDIM + s * 8);
    *(ushort8*)(s_w + a * 1024 + ((s ^ (a & 7)) << 4)) = v;
  }
  __syncthreads();

  // ---- GEMM2: C2[32][32] = h @ W2[e]; 4 waves = 4 output quadrants
  const int mt2 = wave >> 1, at2 = wave & 1;
  const int am = mt2 * 16 + l15;
  const int ba = at2 * 16 + l15;
  f32x4 acc2 = zero;
  #pragma unroll
  for (int ks = 0; ks < 16; ++ks) {
    int sg = ks * 4 + l4;
    bf16x8 af = *(const bf16x8*)(s_x + am * 1024 + ((sg ^ (am & 7)) << 4));
    bf16x8 bfr2 = *(const bf16x8*)(s_w + ba * 1024 + ((sg ^ (ba & 7)) << 4));
    acc2 = __builtin_amdgcn_mfma_f32_16x16x32_bf16(af, bfr2, acc2, 0, 0, 0);
  }
  // ---- epilogue: +b2, scatter to out[token][a]
  {
    float bias2 = b2[e * ADIM + ba];
    #pragma unroll
    for (int r = 0; r < 4; ++r) {
      int m = mt2 * 16 + l4 * 4 + r;
      if (m < mvalid)
        out[(size_t)mylist[tile_lo + m] * ADIM + ba] = acc2[r] + bias2;
    }
  }
}

// ---------------- fallback (only if ws too small): fp32, block per token ----------------
__global__ __launch_bounds__(256) void naive_kernel(
    const float* __restrict__ obs, const float* __restrict__ W1,
    const float* __restrict__ b1, const float* __restrict__ W2,
    const float* __restrict__ b2, const int* __restrict__ pick,
    float* __restrict__ out)
{
  __shared__ float sx[DDIM];
  __shared__ float sh[HDIM];
  const int t = blockIdx.x, tid = threadIdx.x;
  const int e = pick[t];
  const float* x = obs + (size_t)t * DDIM;
  for (int i = tid; i < DDIM; i += 256) sx[i] = x[i];
  __syncthreads();
  const float* w1 = W1 + (size_t)e * DDIM * HDIM;
  for (int j = tid; j < HDIM; j += 256) {
    float a = b1[e * HDIM + j];
    for (int d = 0; d < DDIM; ++d) a = fmaf(sx[d], w1[(size_t)d * HDIM + j], a);
    sh[j] = a > 0.f ? a : 0.f;
  }
  __syncthreads();
  if (tid < ADIM) {
    const float* w2 = W2 + (size_t)e * HDIM * ADIM;
    float a = b2[e * ADIM + tid];
    for (int j = 0; j < HDIM; ++j) a = fmaf(sh[j], w2[(size_t)j * ADIM + tid], a);
    out[(size_t)t * ADIM + tid] = a;
  }
}

extern "C" void kernel_launch(void* const* d_in, const int* in_sizes, int n_in,
                              void* d_out, int out_size, void* d_ws, size_t ws_size,
                              hipStream_t stream)
{
  const float* obs = (const float*)d_in[0];
  const float* W1  = (const float*)d_in[1];
  const float* b1  = (const float*)d_in[2];
  const float* W2  = (const float*)d_in[3];
  const float* b2  = (const float*)d_in[4];
  const int* pick  = (const int*)d_in[5];
  float* out = (float*)d_out;
  (void)in_sizes; (void)n_in; (void)out_size;

  const size_t OFF_LISTS = 64;
  const size_t OFF_W1T   = 262144;                                   // 256KB
  const size_t OFF_W2T   = OFF_W1T + (size_t)NEXP * HDIM * DDIM * 2; // +7.5MB
  const size_t WS_NEEDED = OFF_W2T + (size_t)NEXP * ADIM * HDIM * 2; // ~8.6MB

  if (ws_size < WS_NEEDED) {
    naive_kernel<<<dim3(NTOK), dim3(256), 0, stream>>>(obs, W1, b1, W2, b2, pick, out);
    return;
  }

  char* ws = (char*)d_ws;
  int* counts = (int*)ws;
  int* lists  = (int*)(ws + OFF_LISTS);
  unsigned short* W1T = (unsigned short*)(ws + OFF_W1T);
  unsigned short* W2T = (unsigned short*)(ws + OFF_W2T);

  prep_kernel<<<dim3(NB_W1 + NB_W2 + 1), dim3(256), 0, stream>>>(
      W1, W2, pick, counts, lists, W1T, W2T);
  moe_gemm<<<dim3(NTILE, NEXP), dim3(256), 98304, stream>>>(
      obs, b1, b2, counts, lists, W1T, W2T, out);
}

// Round 2
// 44.627 us; speedup vs baseline: 1.1159x; 1.1159x over previous
//
#include <hip/hip_runtime.h>
#include <stdint.h>

// HeteNet distribute_compute: T=64, N=64, D=512, H=512, A=32, E=15
#define NTOK 4096
#define DDIM 512
#define HDIM 512
#define ADIM 32
#define NEXP 15
#define TILE_M 64
#define MAXTILE 79   // floor(4096/64) + 15 = max possible tiles

typedef __attribute__((ext_vector_type(8))) short bf16x8;
typedef __attribute__((ext_vector_type(8))) unsigned short ushort8;
typedef __attribute__((ext_vector_type(4))) float f32x4;

__device__ __forceinline__ unsigned short f2bf(float f) {
  unsigned int u = __float_as_uint(f);
  u += 0x7fffu + ((u >> 16) & 1u);   // round-to-nearest-even
  return (unsigned short)(u >> 16);
}

__device__ __forceinline__ void gld_lds16(const void* g, void* l) {
  __builtin_amdgcn_global_load_lds(
      (const __attribute__((address_space(1))) void*)g,
      (__attribute__((address_space(3))) void*)l, 16, 0, 0);
}

// ---------------- prep: W transpose+bf16 convert, token bucketing, tile table ----------------
#define NB_W1 (NEXP * 16 * 16)   // 3840 blocks: W1 [E][D][H] -> W1T bf16 [E][H][D]
#define NB_W2 (NEXP * 16)        // 240  blocks: W2 [E][H][A] -> W2T bf16 [E][A][H]

__global__ __launch_bounds__(256) void prep_kernel(
    const float* __restrict__ W1, const float* __restrict__ W2,
    const int* __restrict__ pick, int* __restrict__ meta,
    int* __restrict__ lists, unsigned short* __restrict__ W1T,
    unsigned short* __restrict__ W2T)
{
  const int bid = blockIdx.x;
  const int tid = threadIdx.x;
  if (bid < NB_W1) {
    __shared__ float tile[32][33];
    const int e = bid >> 8, rem = bid & 255, ti = rem >> 4, tj = rem & 15;
    const float* src = W1 + (size_t)e * (DDIM * HDIM);
    unsigned short* dst = W1T + (size_t)e * (HDIM * DDIM);
    const int tx = tid & 31, ty = tid >> 5;
    const int r0 = ti * 32, c0 = tj * 32;  // r0: k (D), c0: n (H)
    #pragma unroll
    for (int r = 0; r < 4; ++r)
      tile[ty + r * 8][tx] = src[(size_t)(r0 + ty + r * 8) * HDIM + (c0 + tx)];
    __syncthreads();
    if (tid < 128) {
      const int j = tid >> 2, q = tid & 3;   // j: out row (H), q: 8-col group (D)
      ushort8 v;
      #pragma unroll
      for (int x = 0; x < 8; ++x) v[x] = f2bf(tile[q * 8 + x][j]);
      *(ushort8*)(dst + (size_t)(c0 + j) * DDIM + r0 + q * 8) = v;
    }
  } else if (bid < NB_W1 + NB_W2) {
    __shared__ float tile2[32][33];
    const int b = bid - NB_W1, e = b >> 4, ti = b & 15;
    const float* src = W2 + (size_t)e * (HDIM * ADIM);
    unsigned short* dst = W2T + (size_t)e * (ADIM * HDIM);
    const int tx = tid & 31, ty = tid >> 5;
    const int r0 = ti * 32;   // k window (H); cols are full A=32
    #pragma unroll
    for (int r = 0; r < 4; ++r)
      tile2[ty + r * 8][tx] = src[(size_t)(r0 + ty + r * 8) * ADIM + tx];
    __syncthreads();
    if (tid < 128) {
      const int j = tid >> 2, q = tid & 3;   // j: out row (A)
      ushort8 v;
      #pragma unroll
      for (int x = 0; x < 8; ++x) v[x] = f2bf(tile2[q * 8 + x][j]);
      *(ushort8*)(dst + (size_t)j * HDIM + r0 + q * 8) = v;
    }
  } else {
    // ordered deterministic per-expert compaction + tile table
    __shared__ int s_inc[NEXP][256];
    __shared__ int s_run[NEXP][256];
    int pk[16];
    #pragma unroll
    for (int i = 0; i < 16; ++i) pk[i] = pick[tid * 16 + i];
    #pragma unroll
    for (int e = 0; e < NEXP; ++e) {
      int c = 0;
      #pragma unroll
      for (int i = 0; i < 16; ++i) c += (pk[i] == e) ? 1 : 0;
      s_inc[e][tid] = c;
    }
    __syncthreads();
    for (int off = 1; off < 256; off <<= 1) {   // Hillis-Steele inclusive scan
      int v[NEXP];
      #pragma unroll
      for (int e = 0; e < NEXP; ++e) v[e] = (tid >= off) ? s_inc[e][tid - off] : 0;
      __syncthreads();
      #pragma unroll
      for (int e = 0; e < NEXP; ++e) s_inc[e][tid] += v[e];
      __syncthreads();
    }
    #pragma unroll
    for (int e = 0; e < NEXP; ++e) s_run[e][tid] = (tid > 0) ? s_inc[e][tid - 1] : 0;
    __syncthreads();
    #pragma unroll
    for (int i = 0; i < 16; ++i) {
      int p = pk[i];
      int pos = s_run[p][tid]++;
      lists[p * NTOK + pos] = tid * 16 + i;
    }
    if (tid < NEXP) meta[tid] = s_inc[tid][255];
    __syncthreads();
    if (tid == 0) {
      int tot = 0;
      for (int ee = 0; ee < NEXP; ++ee) {
        int c = s_inc[ee][255];
        int nt = (c + TILE_M - 1) / TILE_M;
        for (int i = 0; i < nt; ++i) meta[16 + tot++] = (ee << 16) | i;
      }
      meta[15] = tot;
    }
  }
}

// ---------------- fused grouped 2-layer MLP, bf16 MFMA, pipelined gload_lds ----------------
// LDS (128KB dynamic): s_x [64 rows][512 k] bf16 swizzled (64KB) @0
//                      s_w0 (32KB) @65536, s_w1 (32KB) @98304
// W1 chunk layout (linear, gload_lds direct): [512 n][4 slot][16B], row stride 64B
//   -> inherently bank-uniform for B-frag reads (row stride not a mult of 128B)
// W2 layout in s_w0: [32 a][64 slot] swizzled via pre-swizzled global source
__global__ __launch_bounds__(256, 1) void moe_gemm(
    const float* __restrict__ obs, const float* __restrict__ b1,
    const float* __restrict__ b2, const int* __restrict__ meta,
    const int* __restrict__ lists, const unsigned short* __restrict__ W1T,
    const unsigned short* __restrict__ W2T, float* __restrict__ out)
{
  const int ntiles = meta[15];
  if ((int)blockIdx.x >= ntiles) return;
  const int tl = meta[16 + blockIdx.x];
  const int e = tl >> 16;
  const int tile_lo = (tl & 0xffff) * TILE_M;
  const int cnt = meta[e];
  int mvalid = cnt - tile_lo; if (mvalid > TILE_M) mvalid = TILE_M;

  extern __shared__ char smem[];
  char* s_x  = smem;            // 64KB
  char* s_w0 = smem + 65536;    // 32KB
  char* s_w1 = smem + 98304;    // 32KB

  const int tid = threadIdx.x;
  const int lane = tid & 63;
  const int wave = tid >> 6;
  const int l15 = lane & 15, l4 = lane >> 4;
  const int nbase = wave * 128;
  const int* mylist = lists + e * NTOK;
  const unsigned short* w1t_e = W1T + (size_t)e * (HDIM * DDIM);
  const unsigned short* w2t_e = W2T + (size_t)e * (ADIM * HDIM);

  // prefetch b1 for this wave's 128 H-cols
  float b1r[8];
  #pragma unroll
  for (int nt = 0; nt < 8; ++nt) b1r[nt] = b1[e * HDIM + nbase + nt * 16 + l15];

  // ---- issue W1 chunk 0 (async, direct-to-LDS) ----
  #pragma unroll
  for (int i = 0; i < 8; ++i) {
    const int nb = nbase + i * 16;
    const unsigned short* g = w1t_e + (size_t)(nb + (lane >> 2)) * DDIM + (lane & 3) * 8;
    gld_lds16(g, s_w0 + nb * 64);
  }

  // ---- stage X: gather 64 obs rows, fp32->bf16, swizzled 16B slots ----
  {
    const int m = tid >> 2, sq = tid & 3;   // 64 rows, 4 threads/row
    int idx = tile_lo + m; if (idx >= cnt) idx = cnt - 1;
    const float* grow = obs + (size_t)mylist[idx] * DDIM;
    #pragma unroll
    for (int si = 0; si < 16; ++si) {
      const int s = sq + si * 4;
      float4 f0 = *(const float4*)(grow + s * 8);
      float4 f1 = *(const float4*)(grow + s * 8 + 4);
      ushort8 v;
      v[0] = f2bf(f0.x); v[1] = f2bf(f0.y); v[2] = f2bf(f0.z); v[3] = f2bf(f0.w);
      v[4] = f2bf(f1.x); v[5] = f2bf(f1.y); v[6] = f2bf(f1.z); v[7] = f2bf(f1.w);
      *(ushort8*)(s_x + m * 1024 + ((s ^ (m & 7)) << 4)) = v;
    }
  }
  asm volatile("s_waitcnt vmcnt(0)" ::: "memory");
  __syncthreads();

  // ---- GEMM1: C1[64][512] = X @ W1[e]; 16 chunks of K=32, double-buffered ----
  f32x4 zero = {0.f, 0.f, 0.f, 0.f};
  f32x4 acc[4][8];
  #pragma unroll
  for (int mt = 0; mt < 4; ++mt)
    #pragma unroll
    for (int nt = 0; nt < 8; ++nt) acc[mt][nt] = zero;

  for (int t = 0; t < 16; ++t) {
    char* cur = (t & 1) ? s_w1 : s_w0;
    char* nxt = (t & 1) ? s_w0 : s_w1;
    if (t < 15) {
      // issue next W1 chunk before computing current
      #pragma unroll
      for (int i = 0; i < 8; ++i) {
        const int nb = nbase + i * 16;
        const unsigned short* g = w1t_e + (size_t)(nb + (lane >> 2)) * DDIM
                                  + (t + 1) * 32 + (lane & 3) * 8;
        gld_lds16(g, nxt + nb * 64);
      }
    } else {
      // t==15: stage W2T into s_w0 (cur is s_w1; no clash)
      #pragma unroll
      for (int i = 0; i < 8; ++i) {
        const int a = wave * 8 + i;
        const unsigned short* g = w2t_e + (size_t)a * HDIM + (lane ^ (a & 7)) * 8;
        gld_lds16(g, s_w0 + a * 1024);
      }
    }
    __builtin_amdgcn_sched_barrier(0);

    bf16x8 afr[4];
    #pragma unroll
    for (int mt = 0; mt < 4; ++mt) {
      const int m = mt * 16 + l15;
      afr[mt] = *(const bf16x8*)(s_x + m * 1024 + ((((t << 2) + l4) ^ (m & 7)) << 4));
    }
    #pragma unroll
    for (int nt = 0; nt < 8; ++nt) {
      const int n = nbase + nt * 16 + l15;
      bf16x8 bfr = *(const bf16x8*)(cur + n * 64 + (l4 << 4));
      #pragma unroll
      for (int mt = 0; mt < 4; ++mt)
        acc[mt][nt] = __builtin_amdgcn_mfma_f32_16x16x32_bf16(afr[mt], bfr, acc[mt][nt], 0, 0, 0);
    }
    asm volatile("s_waitcnt vmcnt(0)" ::: "memory");
    __syncthreads();
  }

  // ---- h = relu(C1 + b1) -> bf16 back into s_x (all X reads done) ----
  #pragma unroll
  for (int mt = 0; mt < 4; ++mt)
    #pragma unroll
    for (int nt = 0; nt < 8; ++nt) {
      const int n = nbase + nt * 16 + l15;
      #pragma unroll
      for (int r = 0; r < 4; ++r) {
        const int m = mt * 16 + l4 * 4 + r;   // C/D: row=(lane>>4)*4+reg, col=lane&15
        float v = acc[mt][nt][r] + b1r[nt];
        v = fmaxf(v, 0.f);
        *(unsigned short*)(s_x + m * 1024 + (((n >> 3) ^ (m & 7)) << 4) + ((n & 7) << 1)) = f2bf(v);
      }
    }
  __syncthreads();

  // ---- GEMM2: C2[64][32] = h @ W2[e]; wave w owns rows w*16..+16 ----
  f32x4 acc2[2] = {zero, zero};
  #pragma unroll
  for (int ks = 0; ks < 16; ++ks) {
    const int m = wave * 16 + l15;
    bf16x8 af = *(const bf16x8*)(s_x + m * 1024 + ((((ks << 2) + l4) ^ (m & 7)) << 4));
    #pragma unroll
    for (int ct = 0; ct < 2; ++ct) {
      const int a = ct * 16 + l15;
      bf16x8 bfr2 = *(const bf16x8*)(s_w0 + a * 1024 + ((((ks << 2) + l4) ^ (a & 7)) << 4));
      acc2[ct] = __builtin_amdgcn_mfma_f32_16x16x32_bf16(af, bfr2, acc2[ct], 0, 0, 0);
    }
  }
  // ---- epilogue: +b2, scatter ----
  #pragma unroll
  for (int ct = 0; ct < 2; ++ct) {
    const int a = ct * 16 + l15;
    const float bias2 = b2[e * ADIM + a];
    #pragma unroll
    for (int r = 0; r < 4; ++r) {
      const int m = wave * 16 + l4 * 4 + r;
      if (m < mvalid)
        out[(size_t)mylist[tile_lo + m] * ADIM + a] = acc2[ct][r] + bias2;
    }
  }
}

// ---------------- fallback (ws too small): fp32, block per token ----------------
__global__ __launch_bounds__(256) void naive_kernel(
    const float* __restrict__ obs, const float* __restrict__ W1,
    const float* __restrict__ b1, const float* __restrict__ W2,
    const float* __restrict__ b2, const int* __restrict__ pick,
    float* __restrict__ out)
{
  __shared__ float sx[DDIM];
  __shared__ float sh[HDIM];
  const int t = blockIdx.x, tid = threadIdx.x;
  const int e = pick[t];
  const float* x = obs + (size_t)t * DDIM;
  for (int i = tid; i < DDIM; i += 256) sx[i] = x[i];
  __syncthreads();
  const float* w1 = W1 + (size_t)e * DDIM * HDIM;
  for (int j = tid; j < HDIM; j += 256) {
    float a = b1[e * HDIM + j];
    for (int d = 0; d < DDIM; ++d) a = fmaf(sx[d], w1[(size_t)d * HDIM + j], a);
    sh[j] = a > 0.f ? a : 0.f;
  }
  __syncthreads();
  if (tid < ADIM) {
    const float* w2 = W2 + (size_t)e * HDIM * ADIM;
    float a = b2[e * ADIM + tid];
    for (int j = 0; j < HDIM; ++j) a = fmaf(sh[j], w2[(size_t)j * ADIM + tid], a);
    out[(size_t)t * ADIM + tid] = a;
  }
}

extern "C" void kernel_launch(void* const* d_in, const int* in_sizes, int n_in,
                              void* d_out, int out_size, void* d_ws, size_t ws_size,
                              hipStream_t stream)
{
  const float* obs = (const float*)d_in[0];
  const float* W1  = (const float*)d_in[1];
  const float* b1  = (const float*)d_in[2];
  const float* W2  = (const float*)d_in[3];
  const float* b2  = (const float*)d_in[4];
  const int* pick  = (const int*)d_in[5];
  float* out = (float*)d_out;
  (void)in_sizes; (void)n_in; (void)out_size;

  const size_t OFF_LISTS = 512;
  const size_t OFF_W1T   = 262144;                                   // 256KB
  const size_t OFF_W2T   = OFF_W1T + (size_t)NEXP * HDIM * DDIM * 2; // +7.5MB
  const size_t WS_NEEDED = OFF_W2T + (size_t)NEXP * ADIM * HDIM * 2; // ~8.6MB

  if (ws_size < WS_NEEDED) {
    naive_kernel<<<dim3(NTOK), dim3(256), 0, stream>>>(obs, W1, b1, W2, b2, pick, out);
    return;
  }

  char* ws = (char*)d_ws;
  int* meta   = (int*)ws;                  // [0..14] counts, [15] ntiles, [16..94] tiles
  int* lists  = (int*)(ws + OFF_LISTS);
  unsigned short* W1T = (unsigned short*)(ws + OFF_W1T);
  unsigned short* W2T = (unsigned short*)(ws + OFF_W2T);

  prep_kernel<<<dim3(NB_W1 + NB_W2 + 1), dim3(256), 0, stream>>>(
      W1, W2, pick, meta, lists, W1T, W2T);
  moe_gemm<<<dim3(MAXTILE), dim3(256), 131072, stream>>>(
      obs, b1, b2, meta, lists, W1T, W2T, out);
}

// Round 3
// 33.600 us; speedup vs baseline: 1.4821x; 1.3282x over previous
//
#include <hip/hip_runtime.h>
#include <stdint.h>

// HeteNet distribute_compute: T=64, N=64, D=512, H=512, A=32, E=15
#define NTOK 4096
#define DDIM 512
#define HDIM 512
#define ADIM 32
#define NEXP 15
#define TILE_M 32
#define MAXTILE 143   // 4096/32 + 15 partial tiles

typedef __attribute__((ext_vector_type(8))) short bf16x8;
typedef __attribute__((ext_vector_type(8))) unsigned short ushort8;
typedef __attribute__((ext_vector_type(4))) unsigned short ushort4v;
typedef __attribute__((ext_vector_type(4))) float f32x4;

__device__ __forceinline__ unsigned short f2bf(float f) {
  unsigned int u = __float_as_uint(f);
  u += 0x7fffu + ((u >> 16) & 1u);   // round-to-nearest-even
  return (unsigned short)(u >> 16);
}

__device__ __forceinline__ void gld_lds16(const void* g, void* l) {
  __builtin_amdgcn_global_load_lds(
      (const __attribute__((address_space(1))) void*)g,
      (__attribute__((address_space(3))) void*)l, 16, 0, 0);
}

// ---------------- prep: 256 blocks, one per CU ----------------
// blocks 0..239  : (e, kc) -> W1 image chunk: [512 n][4 slot][16B], slot swizzle baked:
//                  physical slot p holds k-sub q = p ^ ((n>>1)&3)  (k = kc*32 + q*8 .. +8)
// blocks 240..254: e -> W2T [32 a][512 k] bf16 (plain)
// block 255      : token bucketing + tile table
__global__ __launch_bounds__(256) void prep_kernel(
    const float* __restrict__ W1, const float* __restrict__ W2,
    const int* __restrict__ pick, int* __restrict__ meta,
    int* __restrict__ lists, unsigned short* __restrict__ W1I,
    unsigned short* __restrict__ W2T)
{
  extern __shared__ char smem[];
  const int bid = blockIdx.x;
  const int tid = threadIdx.x;
  if (bid < 240) {
    float* s = (float*)smem;                       // [32][516] padded fp32
    const int e = bid / 16, kc = bid % 16, r0 = kc * 32;
    const float* src = W1 + (size_t)e * (DDIM * HDIM) + (size_t)r0 * HDIM;
    #pragma unroll
    for (int v = 0; v < 16; ++v) {
      int i = v * 256 + tid;
      int row = i >> 7, col = (i & 127) * 4;
      *(float4*)(s + row * 516 + col) = *(const float4*)(src + (size_t)row * 512 + col);
    }
    __syncthreads();
    unsigned short* dst = W1I + (size_t)(e * 16 + kc) * 512 * 32;
    const int p = tid & 3;
    #pragma unroll
    for (int w = 0; w < 8; ++w) {
      int n = w * 64 + (tid >> 2);
      int q = p ^ ((n >> 1) & 3);
      ushort8 vv;
      #pragma unroll
      for (int x = 0; x < 8; ++x) vv[x] = f2bf(s[(q * 8 + x) * 516 + n]);
      *(ushort8*)(dst + (size_t)n * 32 + p * 8) = vv;
    }
  } else if (bid < 255) {
    float* s = (float*)smem;                       // [512][36] padded fp32
    const int e = bid - 240;
    const float* src = W2 + (size_t)e * (HDIM * ADIM);
    #pragma unroll
    for (int v = 0; v < 16; ++v) {
      int i = v * 256 + tid;
      int row = i >> 3, col = (i & 7) * 4;
      *(float4*)(s + row * 36 + col) = *(const float4*)(src + (size_t)row * 32 + col);
    }
    __syncthreads();
    unsigned short* dst = W2T + (size_t)e * (ADIM * HDIM);
    const int a = tid >> 3, k0 = (tid & 7) * 64;
    #pragma unroll
    for (int w = 0; w < 8; ++w) {
      ushort8 vv;
      #pragma unroll
      for (int x = 0; x < 8; ++x) vv[x] = f2bf(s[(size_t)(k0 + w * 8 + x) * 36 + a]);
      *(ushort8*)(dst + (size_t)a * 512 + k0 + w * 8) = vv;
    }
  } else {
    // ordered deterministic per-expert compaction + tile table
    int* s_inc = (int*)smem;            // [15][256]
    int* s_run = s_inc + NEXP * 256;    // [15][256]
    int pk[16];
    #pragma unroll
    for (int i = 0; i < 16; ++i) pk[i] = pick[tid * 16 + i];
    #pragma unroll
    for (int e = 0; e < NEXP; ++e) {
      int c = 0;
      #pragma unroll
      for (int i = 0; i < 16; ++i) c += (pk[i] == e) ? 1 : 0;
      s_inc[e * 256 + tid] = c;
    }
    __syncthreads();
    for (int off = 1; off < 256; off <<= 1) {
      int v[NEXP];
      #pragma unroll
      for (int e = 0; e < NEXP; ++e) v[e] = (tid >= off) ? s_inc[e * 256 + tid - off] : 0;
      __syncthreads();
      #pragma unroll
      for (int e = 0; e < NEXP; ++e) s_inc[e * 256 + tid] += v[e];
      __syncthreads();
    }
    #pragma unroll
    for (int e = 0; e < NEXP; ++e) s_run[e * 256 + tid] = (tid > 0) ? s_inc[e * 256 + tid - 1] : 0;
    __syncthreads();
    #pragma unroll
    for (int i = 0; i < 16; ++i) {
      int p = pk[i];
      int pos = s_run[p * 256 + tid]++;
      lists[p * NTOK + pos] = tid * 16 + i;
    }
    if (tid < NEXP) meta[tid] = s_inc[tid * 256 + 255];
    __syncthreads();
    if (tid == 0) {
      int tot = 0;
      for (int ee = 0; ee < NEXP; ++ee) {
        int c = s_inc[ee * 256 + 255];
        int nt = (c + TILE_M - 1) / TILE_M;
        for (int i = 0; i < nt; ++i) meta[16 + tot++] = (ee << 16) | i;
      }
      meta[15] = tot;
    }
  }
}

// ---------------- fused grouped MLP: barrier-free K-loop, counted vmcnt ----------------
// LDS (128KB): s_x [32 m][512 k] bf16 swizzled (32KB) @0; wb0/1/2 32KB W chunk bufs.
// Wave w stages AND reads only W rows [w*128, w*128+128) -> no barrier in K loop.
__global__ __launch_bounds__(256, 1) void moe_gemm(
    const float* __restrict__ obs, const float* __restrict__ b1,
    const float* __restrict__ b2, const int* __restrict__ meta,
    const int* __restrict__ lists, const unsigned short* __restrict__ W1I,
    const unsigned short* __restrict__ W2T, float* __restrict__ out)
{
  const int ntiles = meta[15];
  if ((int)blockIdx.x >= ntiles) return;
  const int tl = meta[16 + blockIdx.x];
  const int e = tl >> 16;
  const int tile_lo = (tl & 0xffff) * TILE_M;
  const int cnt = meta[e];
  int mvalid = cnt - tile_lo; if (mvalid > TILE_M) mvalid = TILE_M;

  extern __shared__ char smem[];
  char* s_x = smem;                                   // 32KB
  char* wb0 = smem + 32768;
  char* wb1 = smem + 65536;
  char* wb2 = smem + 98304;

  const int tid = threadIdx.x, lane = tid & 63, wave = tid >> 6;
  const int l15 = lane & 15, l4 = lane >> 4;
  const int nbase = wave * 128;
  const int* mylist = lists + e * NTOK;
  const unsigned short* w1i_e = W1I + (size_t)e * 16 * 512 * 32;
  const unsigned short* w2t_e = W2T + (size_t)e * (ADIM * HDIM);

  // ---- issue X gather loads first (oldest in vmcnt queue) ----
  const int m = tid >> 3, s8 = tid & 7;
  int idx = tile_lo + m; if (idx >= cnt) idx = cnt - 1;
  const float* grow = obs + (size_t)mylist[idx] * DDIM;
  float4 xf[16];
  #pragma unroll
  for (int si = 0; si < 8; ++si) {
    xf[si * 2]     = *(const float4*)(grow + (s8 + si * 8) * 8);
    xf[si * 2 + 1] = *(const float4*)(grow + (s8 + si * 8) * 8 + 4);
  }

  // ---- issue W1 chunks 0,1 (async -> LDS, per-wave own rows) ----
  auto issue_w1 = [&](int t, char* buf) {
    const unsigned short* base = w1i_e + (size_t)t * (512 * 32);
    #pragma unroll
    for (int i = 0; i < 8; ++i) {
      int nb = nbase + i * 16;
      gld_lds16(base + (size_t)nb * 32 + lane * 8, buf + nb * 64);
    }
  };
  issue_w1(0, wb0);
  issue_w1(1, wb1);

  // ---- convert + store X to LDS (consuming X forces only X retirement) ----
  #pragma unroll
  for (int si = 0; si < 8; ++si) {
    int s = s8 + si * 8;
    float4 f0 = xf[si * 2], f1 = xf[si * 2 + 1];
    ushort8 v;
    v[0] = f2bf(f0.x); v[1] = f2bf(f0.y); v[2] = f2bf(f0.z); v[3] = f2bf(f0.w);
    v[4] = f2bf(f1.x); v[5] = f2bf(f1.y); v[6] = f2bf(f1.z); v[7] = f2bf(f1.w);
    *(ushort8*)(s_x + m * 1024 + ((s ^ (m & 7)) << 4)) = v;
  }
  __syncthreads();

  // ---- acc init = b1 bias (C1^T: row = n-local, col = m) ----
  f32x4 acc[8][2];
  #pragma unroll
  for (int nt = 0; nt < 8; ++nt) {
    float4 bv = *(const float4*)(b1 + e * HDIM + nbase + nt * 16 + l4 * 4);
    f32x4 b4 = {bv.x, bv.y, bv.z, bv.w};
    acc[nt][0] = b4; acc[nt][1] = b4;
  }

  // ---- GEMM1 (swapped): acc[nt][mt] += W1frag x Xfrag; no barriers, counted vmcnt ----
  #pragma unroll
  for (int t = 0; t < 16; ++t) {
    if (t < 14) {
      char* nxt = ((t + 2) % 3 == 0) ? wb0 : ((t + 2) % 3 == 1) ? wb1 : wb2;
      issue_w1(t + 2, nxt);
    } else if (t == 14) {
      // stage W2 -> wb1 (last read of wb1 was chunk 13); pre-swizzled source
      #pragma unroll
      for (int i = 0; i < 8; ++i) {
        int a = wave * 8 + i;
        gld_lds16(w2t_e + (size_t)a * 512 + (size_t)(lane ^ (a & 7)) * 8, wb1 + a * 1024);
      }
    }
    if (t < 15) asm volatile("s_waitcnt vmcnt(16)" ::: "memory");
    else        asm volatile("s_waitcnt vmcnt(8)" ::: "memory");
    __builtin_amdgcn_sched_barrier(0);

    const char* cw = (t % 3 == 0) ? wb0 : (t % 3 == 1) ? wb1 : wb2;
    bf16x8 wfr[8], xfr[2];
    #pragma unroll
    for (int nt = 0; nt < 8; ++nt) {
      int n = nbase + nt * 16 + l15;
      wfr[nt] = *(const bf16x8*)(cw + n * 64 + ((l4 ^ ((n >> 1) & 3)) << 4));
    }
    #pragma unroll
    for (int mt = 0; mt < 2; ++mt) {
      int mm = mt * 16 + l15;
      xfr[mt] = *(const bf16x8*)(s_x + mm * 1024 + ((((t << 2) + l4) ^ (mm & 7)) << 4));
    }
    #pragma unroll
    for (int nt = 0; nt < 8; ++nt)
      #pragma unroll
      for (int mt = 0; mt < 2; ++mt)
        acc[nt][mt] = __builtin_amdgcn_mfma_f32_16x16x32_bf16(wfr[nt], xfr[mt], acc[nt][mt], 0, 0, 0);
  }

  __syncthreads();   // all waves finished reading s_x

  // ---- h = relu(acc) -> bf16 into s_x; lane writes 4 consecutive n as b64 ----
  #pragma unroll
  for (int nt = 0; nt < 8; ++nt) {
    int n0 = nbase + nt * 16 + l4 * 4;
    int sg = n0 >> 3, half = (n0 >> 2) & 1;
    #pragma unroll
    for (int mt = 0; mt < 2; ++mt) {
      int mm = mt * 16 + l15;
      ushort4v hv;
      #pragma unroll
      for (int r = 0; r < 4; ++r) hv[r] = f2bf(fmaxf(acc[nt][mt][r], 0.f));
      *(ushort4v*)(s_x + mm * 1024 + ((sg ^ (mm & 7)) << 4) + half * 8) = hv;
    }
  }
  __syncthreads();   // h complete; W2 landed (implicit vmcnt(0) drain)

  // ---- GEMM2: C2[32 m][32 a] = h @ W2; wave quadrant (mt2, at2) ----
  const int mt2 = wave >> 1, at2 = wave & 1;
  const float b2v = b2[e * ADIM + at2 * 16 + l15];
  f32x4 acc2 = {b2v, b2v, b2v, b2v};
  #pragma unroll
  for (int ks = 0; ks < 16; ++ks) {
    int mm = mt2 * 16 + l15;
    bf16x8 af = *(const bf16x8*)(s_x + mm * 1024 + ((((ks << 2) + l4) ^ (mm & 7)) << 4));
    int a = at2 * 16 + l15;
    bf16x8 bf = *(const bf16x8*)(wb1 + a * 1024 + ((((ks << 2) + l4) ^ (a & 7)) << 4));
    acc2 = __builtin_amdgcn_mfma_f32_16x16x32_bf16(af, bf, acc2, 0, 0, 0);
  }
  #pragma unroll
  for (int r = 0; r < 4; ++r) {
    int mrow = mt2 * 16 + l4 * 4 + r;
    if (mrow < mvalid)
      out[(size_t)mylist[tile_lo + mrow] * ADIM + at2 * 16 + l15] = acc2[r];
  }
}

// ---------------- fallback (ws too small): fp32, block per token ----------------
__global__ __launch_bounds__(256) void naive_kernel(
    const float* __restrict__ obs, const float* __restrict__ W1,
    const float* __restrict__ b1, const float* __restrict__ W2,
    const float* __restrict__ b2, const int* __restrict__ pick,
    float* __restrict__ out)
{
  __shared__ float sx[DDIM];
  __shared__ float sh[HDIM];
  const int t = blockIdx.x, tid = threadIdx.x;
  const int e = pick[t];
  const float* x = obs + (size_t)t * DDIM;
  for (int i = tid; i < DDIM; i += 256) sx[i] = x[i];
  __syncthreads();
  const float* w1 = W1 + (size_t)e * DDIM * HDIM;
  for (int j = tid; j < HDIM; j += 256) {
    float a = b1[e * HDIM + j];
    for (int d = 0; d < DDIM; ++d) a = fmaf(sx[d], w1[(size_t)d * HDIM + j], a);
    sh[j] = a > 0.f ? a : 0.f;
  }
  __syncthreads();
  if (tid < ADIM) {
    const float* w2 = W2 + (size_t)e * HDIM * ADIM;
    float a = b2[e * ADIM + tid];
    for (int j = 0; j < HDIM; ++j) a = fmaf(sh[j], w2[(size_t)j * ADIM + tid], a);
    out[(size_t)t * ADIM + tid] = a;
  }
}

extern "C" void kernel_launch(void* const* d_in, const int* in_sizes, int n_in,
                              void* d_out, int out_size, void* d_ws, size_t ws_size,
                              hipStream_t stream)
{
  const float* obs = (const float*)d_in[0];
  const float* W1  = (const float*)d_in[1];
  const float* b1  = (const float*)d_in[2];
  const float* W2  = (const float*)d_in[3];
  const float* b2  = (const float*)d_in[4];
  const int* pick  = (const int*)d_in[5];
  float* out = (float*)d_out;
  (void)in_sizes; (void)n_in; (void)out_size;

  const size_t OFF_LISTS = 1024;
  const size_t OFF_W1I   = 262144;                                   // 256KB
  const size_t OFF_W2T   = OFF_W1I + (size_t)NEXP * HDIM * DDIM * 2; // +7.5MB
  const size_t WS_NEEDED = OFF_W2T + (size_t)NEXP * ADIM * HDIM * 2; // ~8.6MB

  if (ws_size < WS_NEEDED) {
    naive_kernel<<<dim3(NTOK), dim3(256), 0, stream>>>(obs, W1, b1, W2, b2, pick, out);
    return;
  }

  char* ws = (char*)d_ws;
  int* meta   = (int*)ws;                  // [0..14] counts, [15] ntiles, [16..158] tiles
  int* lists  = (int*)(ws + OFF_LISTS);
  unsigned short* W1I = (unsigned short*)(ws + OFF_W1I);
  unsigned short* W2T = (unsigned short*)(ws + OFF_W2T);

  prep_kernel<<<dim3(256), dim3(256), 73728, stream>>>(
      W1, W2, pick, meta, lists, W1I, W2T);
  moe_gemm<<<dim3(MAXTILE), dim3(256), 131072, stream>>>(
      obs, b1, b2, meta, lists, W1I, W2T, out);
}

// Round 4
// 28.009 us; speedup vs baseline: 1.7779x; 1.1996x over previous
//
#include <hip/hip_runtime.h>
#include <stdint.h>

// HeteNet distribute_compute: T=64, N=64, D=512, H=512, A=32, E=15
#define NTOK 4096
#define DDIM 512
#define HDIM 512
#define ADIM 32
#define NEXP 15
#define TILE_M 32
#define MAXTILE 143    // max logical tiles: 4096/32 + 15 partials
#define GRID_M 152     // physical grid: covers 8*(q+1) for any ntiles<=143

typedef __attribute__((ext_vector_type(8))) short bf16x8;
typedef __attribute__((ext_vector_type(8))) unsigned short ushort8;
typedef __attribute__((ext_vector_type(4))) unsigned short ushort4v;
typedef __attribute__((ext_vector_type(4))) float f32x4;

__device__ __forceinline__ unsigned short f2bf(float f) {
  unsigned int u = __float_as_uint(f);
  u += 0x7fffu + ((u >> 16) & 1u);   // round-to-nearest-even
  return (unsigned short)(u >> 16);
}

__device__ __forceinline__ void gld_lds16(const void* g, void* l) {
  __builtin_amdgcn_global_load_lds(
      (const __attribute__((address_space(1))) void*)g,
      (__attribute__((address_space(3))) void*)l, 16, 0, 0);
}

// ---------------- prep: 256 blocks, one per CU ----------------
// blocks 0..239  : (e, kc) -> W1 image chunk: [512 n][4 slot][16B], slot swizzle baked:
//                  physical slot p holds k-sub q = p ^ ((n>>1)&3)  (k = kc*32 + q*8 .. +8)
// blocks 240..254: e -> W2T [32 a][512 k] bf16 (plain)
// block 255      : token bucketing + tile table
__global__ __launch_bounds__(256) void prep_kernel(
    const float* __restrict__ W1, const float* __restrict__ W2,
    const int* __restrict__ pick, int* __restrict__ meta,
    int* __restrict__ lists, unsigned short* __restrict__ W1I,
    unsigned short* __restrict__ W2T)
{
  extern __shared__ char smem[];
  const int bid = blockIdx.x;
  const int tid = threadIdx.x;
  if (bid < 240) {
    float* s = (float*)smem;                       // [32][517] padded fp32
    const int e = bid / 16, kc = bid % 16, r0 = kc * 32;
    const float* src = W1 + (size_t)e * (DDIM * HDIM) + (size_t)r0 * HDIM;
    #pragma unroll
    for (int v = 0; v < 16; ++v) {
      int i = v * 256 + tid;
      int row = i >> 7, col = (i & 127) * 4;
      *(float4*)(s + row * 517 + col) = *(const float4*)(src + (size_t)row * 512 + col);
    }
    __syncthreads();
    unsigned short* dst = W1I + (size_t)(e * 16 + kc) * 512 * 32;
    const int p = tid & 3;
    #pragma unroll
    for (int w = 0; w < 8; ++w) {
      int n = w * 64 + (tid >> 2);
      int q = p ^ ((n >> 1) & 3);
      ushort8 vv;
      #pragma unroll
      for (int x = 0; x < 8; ++x) vv[x] = f2bf(s[(q * 8 + x) * 517 + n]);
      *(ushort8*)(dst + (size_t)n * 32 + p * 8) = vv;
    }
  } else if (bid < 255) {
    float* s = (float*)smem;                       // [512][36] padded fp32
    const int e = bid - 240;
    const float* src = W2 + (size_t)e * (HDIM * ADIM);
    #pragma unroll
    for (int v = 0; v < 16; ++v) {
      int i = v * 256 + tid;
      int row = i >> 3, col = (i & 7) * 4;
      *(float4*)(s + row * 36 + col) = *(const float4*)(src + (size_t)row * 32 + col);
    }
    __syncthreads();
    unsigned short* dst = W2T + (size_t)e * (ADIM * HDIM);
    const int a = tid >> 3, k0 = (tid & 7) * 64;
    #pragma unroll
    for (int w = 0; w < 8; ++w) {
      ushort8 vv;
      #pragma unroll
      for (int x = 0; x < 8; ++x) vv[x] = f2bf(s[(size_t)(k0 + w * 8 + x) * 36 + a]);
      *(ushort8*)(dst + (size_t)a * 512 + k0 + w * 8) = vv;
    }
  } else {
    // ordered deterministic per-expert compaction + tile table
    int* s_inc = (int*)smem;            // [15][256]
    int* s_run = s_inc + NEXP * 256;    // [15][256]
    int pk[16];
    #pragma unroll
    for (int i = 0; i < 16; ++i) pk[i] = pick[tid * 16 + i];
    #pragma unroll
    for (int e = 0; e < NEXP; ++e) {
      int c = 0;
      #pragma unroll
      for (int i = 0; i < 16; ++i) c += (pk[i] == e) ? 1 : 0;
      s_inc[e * 256 + tid] = c;
    }
    __syncthreads();
    for (int off = 1; off < 256; off <<= 1) {
      int v[NEXP];
      #pragma unroll
      for (int e = 0; e < NEXP; ++e) v[e] = (tid >= off) ? s_inc[e * 256 + tid - off] : 0;
      __syncthreads();
      #pragma unroll
      for (int e = 0; e < NEXP; ++e) s_inc[e * 256 + tid] += v[e];
      __syncthreads();
    }
    #pragma unroll
    for (int e = 0; e < NEXP; ++e) s_run[e * 256 + tid] = (tid > 0) ? s_inc[e * 256 + tid - 1] : 0;
    __syncthreads();
    #pragma unroll
    for (int i = 0; i < 16; ++i) {
      int p = pk[i];
      int pos = s_run[p * 256 + tid]++;
      lists[p * NTOK + pos] = tid * 16 + i;
    }
    if (tid < NEXP) meta[tid] = s_inc[tid * 256 + 255];
    __syncthreads();
    if (tid == 0) {
      int tot = 0;
      for (int ee = 0; ee < NEXP; ++ee) {
        int c = s_inc[ee * 256 + 255];
        int nt = (c + TILE_M - 1) / TILE_M;
        for (int i = 0; i < nt; ++i) meta[16 + tot++] = (ee << 16) | i;
      }
      meta[15] = tot;
    }
  }
}

// ---------------- fused grouped MLP: barrier-free K-loop, counted vmcnt ----------------
// LDS (128KB): s_x [32 m][512 k] bf16 swizzled (32KB) @0; wb0/1/2 32KB W chunk bufs.
// Wave w stages AND reads only W rows [w*128, w*128+128) -> no barrier in K loop.
// XCD-chunked tile mapping: physical block p on XCD p%8 takes a contiguous slice of
// the expert-sorted tile list -> same-expert W1I stays in one XCD's L2.
__global__ __launch_bounds__(256, 1) void moe_gemm(
    const float* __restrict__ obs, const float* __restrict__ b1,
    const float* __restrict__ b2, const int* __restrict__ meta,
    const int* __restrict__ lists, const unsigned short* __restrict__ W1I,
    const unsigned short* __restrict__ W2T, float* __restrict__ out)
{
  const int ntiles = meta[15];
  const int p = blockIdx.x;
  const int xq = ntiles >> 3, xr = ntiles & 7;
  const int xcd = p & 7, slot = p >> 3;
  const int cx = xq + (xcd < xr ? 1 : 0);
  if (slot >= cx) return;
  const int j = xcd * xq + (xcd < xr ? xcd : xr) + slot;   // logical tile (bijective)

  const int tl = meta[16 + j];
  const int e = tl >> 16;
  const int tile_lo = (tl & 0xffff) * TILE_M;
  const int cnt = meta[e];
  int mvalid = cnt - tile_lo; if (mvalid > TILE_M) mvalid = TILE_M;

  extern __shared__ char smem[];
  char* s_x = smem;                                   // 32KB
  char* wb0 = smem + 32768;
  char* wb1 = smem + 65536;
  char* wb2 = smem + 98304;

  const int tid = threadIdx.x, lane = tid & 63, wave = tid >> 6;
  const int l15 = lane & 15, l4 = lane >> 4;
  const int nbase = wave * 128;
  const int* mylist = lists + e * NTOK;
  const unsigned short* w1i_e = W1I + (size_t)e * 16 * 512 * 32;
  const unsigned short* w2t_e = W2T + (size_t)e * (ADIM * HDIM);

  // ---- issue X gather loads first (oldest in vmcnt queue) ----
  const int m = tid >> 3, s8 = tid & 7;
  int idx = tile_lo + m; if (idx >= cnt) idx = cnt - 1;
  const float* grow = obs + (size_t)mylist[idx] * DDIM;
  float4 xf[16];
  #pragma unroll
  for (int si = 0; si < 8; ++si) {
    xf[si * 2]     = *(const float4*)(grow + (s8 + si * 8) * 8);
    xf[si * 2 + 1] = *(const float4*)(grow + (s8 + si * 8) * 8 + 4);
  }
  __builtin_amdgcn_sched_barrier(0);

  // ---- issue W1 chunks 0,1 (async -> LDS, per-wave own rows); keep groups ordered ----
  auto issue_w1 = [&](int t, char* buf) {
    const unsigned short* base = w1i_e + (size_t)t * (512 * 32);
    #pragma unroll
    for (int i = 0; i < 8; ++i) {
      int nb = nbase + i * 16;
      gld_lds16(base + (size_t)nb * 32 + lane * 8, buf + nb * 64);
    }
  };
  issue_w1(0, wb0);
  __builtin_amdgcn_sched_barrier(0);
  issue_w1(1, wb1);
  __builtin_amdgcn_sched_barrier(0);

  // ---- convert + store X to LDS (consuming xf retires all X loads) ----
  #pragma unroll
  for (int si = 0; si < 8; ++si) {
    int s = s8 + si * 8;
    float4 f0 = xf[si * 2], f1 = xf[si * 2 + 1];
    ushort8 v;
    v[0] = f2bf(f0.x); v[1] = f2bf(f0.y); v[2] = f2bf(f0.z); v[3] = f2bf(f0.w);
    v[4] = f2bf(f1.x); v[5] = f2bf(f1.y); v[6] = f2bf(f1.z); v[7] = f2bf(f1.w);
    *(ushort8*)(s_x + m * 1024 + ((s ^ (m & 7)) << 4)) = v;
  }
  __syncthreads();

  // ---- acc init = b1 bias (C1^T: row = n-local, col = m); consumed immediately ----
  f32x4 acc[8][2];
  #pragma unroll
  for (int nt = 0; nt < 8; ++nt) {
    float4 bv = *(const float4*)(b1 + e * HDIM + nbase + nt * 16 + l4 * 4);
    f32x4 b4 = {bv.x, bv.y, bv.z, bv.w};
    acc[nt][0] = b4; acc[nt][1] = b4;
  }

  // ---- GEMM1 (swapped): acc[nt][mt] += W1frag x Xfrag; no barriers, counted vmcnt ----
  #pragma unroll
  for (int t = 0; t < 16; ++t) {
    if (t < 14) {
      char* nxt = ((t + 2) % 3 == 0) ? wb0 : ((t + 2) % 3 == 1) ? wb1 : wb2;
      issue_w1(t + 2, nxt);
    } else if (t == 14) {
      // stage W2 -> wb1 (last read of wb1 was chunk 13); pre-swizzled source
      #pragma unroll
      for (int i = 0; i < 8; ++i) {
        int a = wave * 8 + i;
        gld_lds16(w2t_e + (size_t)a * 512 + (size_t)(lane ^ (a & 7)) * 8, wb1 + a * 1024);
      }
    }
    if (t < 15) asm volatile("s_waitcnt vmcnt(16)" ::: "memory");
    else        asm volatile("s_waitcnt vmcnt(8)" ::: "memory");
    __builtin_amdgcn_sched_barrier(0);

    const char* cw = (t % 3 == 0) ? wb0 : (t % 3 == 1) ? wb1 : wb2;
    bf16x8 wfr[8], xfr[2];
    #pragma unroll
    for (int nt = 0; nt < 8; ++nt) {
      int n = nbase + nt * 16 + l15;
      wfr[nt] = *(const bf16x8*)(cw + n * 64 + ((l4 ^ ((n >> 1) & 3)) << 4));
    }
    #pragma unroll
    for (int mt = 0; mt < 2; ++mt) {
      int mm = mt * 16 + l15;
      xfr[mt] = *(const bf16x8*)(s_x + mm * 1024 + ((((t << 2) + l4) ^ (mm & 7)) << 4));
    }
    #pragma unroll
    for (int nt = 0; nt < 8; ++nt)
      #pragma unroll
      for (int mt = 0; mt < 2; ++mt)
        acc[nt][mt] = __builtin_amdgcn_mfma_f32_16x16x32_bf16(wfr[nt], xfr[mt], acc[nt][mt], 0, 0, 0);
  }

  __syncthreads();   // all waves finished reading s_x

  // ---- h = relu(acc) -> bf16 into s_x; lane writes 4 consecutive n as b64 ----
  #pragma unroll
  for (int nt = 0; nt < 8; ++nt) {
    int n0 = nbase + nt * 16 + l4 * 4;
    int sg = n0 >> 3, half = (n0 >> 2) & 1;
    #pragma unroll
    for (int mt = 0; mt < 2; ++mt) {
      int mm = mt * 16 + l15;
      ushort4v hv;
      #pragma unroll
      for (int r = 0; r < 4; ++r) hv[r] = f2bf(fmaxf(acc[nt][mt][r], 0.f));
      *(ushort4v*)(s_x + mm * 1024 + ((sg ^ (mm & 7)) << 4) + half * 8) = hv;
    }
  }
  __syncthreads();   // h complete; W2 landed (implicit vmcnt(0) drain)

  // ---- GEMM2: C2[32 m][32 a] = h @ W2; wave quadrant (mt2, at2) ----
  const int mt2 = wave >> 1, at2 = wave & 1;
  const float b2v = b2[e * ADIM + at2 * 16 + l15];
  f32x4 acc2 = {b2v, b2v, b2v, b2v};
  #pragma unroll
  for (int ks = 0; ks < 16; ++ks) {
    int mm = mt2 * 16 + l15;
    bf16x8 af = *(const bf16x8*)(s_x + mm * 1024 + ((((ks << 2) + l4) ^ (mm & 7)) << 4));
    int a = at2 * 16 + l15;
    bf16x8 bf = *(const bf16x8*)(wb1 + a * 1024 + ((((ks << 2) + l4) ^ (a & 7)) << 4));
    acc2 = __builtin_amdgcn_mfma_f32_16x16x32_bf16(af, bf, acc2, 0, 0, 0);
  }
  #pragma unroll
  for (int r = 0; r < 4; ++r) {
    int mrow = mt2 * 16 + l4 * 4 + r;
    if (mrow < mvalid)
      out[(size_t)mylist[tile_lo + mrow] * ADIM + at2 * 16 + l15] = acc2[r];
  }
}

// ---------------- fallback (ws too small): fp32, block per token ----------------
__global__ __launch_bounds__(256) void naive_kernel(
    const float* __restrict__ obs, const float* __restrict__ W1,
    const float* __restrict__ b1, const float* __restrict__ W2,
    const float* __restrict__ b2, const int* __restrict__ pick,
    float* __restrict__ out)
{
  __shared__ float sx[DDIM];
  __shared__ float sh[HDIM];
  const int t = blockIdx.x, tid = threadIdx.x;
  const int e = pick[t];
  const float* x = obs + (size_t)t * DDIM;
  for (int i = tid; i < DDIM; i += 256) sx[i] = x[i];
  __syncthreads();
  const float* w1 = W1 + (size_t)e * DDIM * HDIM;
  for (int j = tid; j < HDIM; j += 256) {
    float a = b1[e * HDIM + j];
    for (int d = 0; d < DDIM; ++d) a = fmaf(sx[d], w1[(size_t)d * HDIM + j], a);
    sh[j] = a > 0.f ? a : 0.f;
  }
  __syncthreads();
  if (tid < ADIM) {
    const float* w2 = W2 + (size_t)e * HDIM * ADIM;
    float a = b2[e * ADIM + tid];
    for (int j = 0; j < HDIM; ++j) a = fmaf(sh[j], w2[(size_t)j * ADIM + tid], a);
    out[(size_t)t * ADIM + tid] = a;
  }
}

extern "C" void kernel_launch(void* const* d_in, const int* in_sizes, int n_in,
                              void* d_out, int out_size, void* d_ws, size_t ws_size,
                              hipStream_t stream)
{
  const float* obs = (const float*)d_in[0];
  const float* W1  = (const float*)d_in[1];
  const float* b1  = (const float*)d_in[2];
  const float* W2  = (const float*)d_in[3];
  const float* b2  = (const float*)d_in[4];
  const int* pick  = (const int*)d_in[5];
  float* out = (float*)d_out;
  (void)in_sizes; (void)n_in; (void)out_size;

  const size_t OFF_LISTS = 1024;
  const size_t OFF_W1I   = 262144;                                   // 256KB
  const size_t OFF_W2T   = OFF_W1I + (size_t)NEXP * HDIM * DDIM * 2; // +7.5MB
  const size_t WS_NEEDED = OFF_W2T + (size_t)NEXP * ADIM * HDIM * 2; // ~8.6MB

  if (ws_size < WS_NEEDED) {
    naive_kernel<<<dim3(NTOK), dim3(256), 0, stream>>>(obs, W1, b1, W2, b2, pick, out);
    return;
  }

  char* ws = (char*)d_ws;
  int* meta   = (int*)ws;                  // [0..14] counts, [15] ntiles, [16..158] tiles
  int* lists  = (int*)(ws + OFF_LISTS);
  unsigned short* W1I = (unsigned short*)(ws + OFF_W1I);
  unsigned short* W2T = (unsigned short*)(ws + OFF_W2T);

  prep_kernel<<<dim3(256), dim3(256), 73728, stream>>>(
      W1, W2, pick, meta, lists, W1I, W2T);
  moe_gemm<<<dim3(GRID_M), dim3(256), 131072, stream>>>(
      obs, b1, b2, meta, lists, W1I, W2T, out);
}